// Round 6
// baseline (358.575 us; speedup 1.0000x reference)
//
#include <hip/hip_runtime.h>
#include <stdint.h>

#define NB 8
#define NPRED 25200
#define NTOP 1000
#define NCLS 80
#define CONF_T 0.25f
#define IOU_THR 0.45f
#define MAXWH 4096.0f
#define CAP 2048
#define NBINS 1025
#define SBLK 128
#define SBPB 197   // ceil(25200/128): 197*128 = 25216

typedef unsigned long long u64;

// ---------------------------------------------------------------------------
// K1: score/class per pred + global histogram of score bits.
// Staging via global_load_lds width=16 (no VGPR round trip).
// ---------------------------------------------------------------------------
__global__ __launch_bounds__(128) void k_score(const float* __restrict__ x,
                                               float* __restrict__ msc,
                                               int* __restrict__ cls,
                                               unsigned* __restrict__ hist) {
#pragma clang fp contract(off)
    __shared__ __align__(16) float sm[SBLK * 85];
    const int b = blockIdx.x / SBPB;
    const int blk = blockIdx.x % SBPB;
    const int t = threadIdx.x;
    const int wave = t >> 6, lane = t & 63;
    const long long TOT4 = (long long)NB * NPRED * 85 / 4;  // 4,284,000
    const long long base4 = ((long long)b * NPRED + (long long)blk * SBLK) * 85 / 4;
    const float4* x4 = (const float4*)x;
    const int tile4 = SBLK * 85 / 4;  // 2720

    for (int k = 0; k < 22; ++k) {
        int ib = k * 128 + wave * 64;      // wave-uniform lds base (float4 units)
        int fi = ib + lane;
        if (fi < tile4) {
            long long gi = base4 + fi;
            if (gi >= TOT4) gi = TOT4 - 1;  // tail clamp (outputs guarded below)
            __builtin_amdgcn_global_load_lds(
                (const __attribute__((address_space(1))) void*)(x4 + gi),
                (__attribute__((address_space(3))) void*)(sm + (size_t)ib * 4),
                16, 0, 0);
        }
    }
    __syncthreads();

    int pred = blk * SBLK + t;
    if (pred < NPRED) {
        const float* p = &sm[t * 85];
        float obj = p[4];
        float best = p[5];
        int bid = 0;
        for (int c = 1; c < NCLS; ++c) {
            float v = p[5 + c];
            if (v > best) { best = v; bid = c; }  // strict >: first occurrence
        }
        float score = obj * best;
        int q = b * NPRED + pred;
        msc[q] = (score > CONF_T) ? score : -1.0f;
        cls[q] = bid;
        if (score > CONF_T) {
            int bin = (int)(__float_as_uint(score) >> 14) - 0xFA00;
            bin = bin < 0 ? 0 : (bin > 1024 ? 1024 : bin);
            atomicAdd(&hist[b * NBINS + bin], 1u);
        }
    }
}

// ---------------------------------------------------------------------------
// K2: per-batch boundary bin B (suffix count >= 1000). 8 waves, wave = batch.
// ---------------------------------------------------------------------------
__global__ __launch_bounds__(512) void k_boundary(const unsigned* __restrict__ hist,
                                                  int* __restrict__ Bv) {
    int b = threadIdx.x >> 6, lane = threadIdx.x & 63;
    const unsigned* h = hist + b * NBINS;
    int hi = 1024 - 16 * lane;           // lane chunk: bins [hi-15, hi]
    unsigned sum = 0;
    for (int k = 0; k < 16; ++k) sum += h[hi - k];
    if (lane == 63) sum += h[0];
    unsigned v = sum;
    for (int d = 1; d < 64; d <<= 1) {
        unsigned o = __shfl_up(v, d);
        if (lane >= d) v += o;
    }
    unsigned excl = v - sum;             // count strictly above my chunk
    u64 ball = __ballot(v >= NTOP);
    int B = 0;
    if (ball != 0) {
        int sel = __builtin_ctzll(ball);
        if (lane == sel) {
            unsigned run = excl;
            for (int k = 0; k < 16; ++k) {
                run += h[hi - k];
                if (run >= NTOP) { B = hi - k; break; }
            }
        }
        B = __shfl(B, sel);
    }
    if (lane == 0) Bv[b] = B;
}

// ---------------------------------------------------------------------------
// K3: compact candidates (bin >= B), one pred per thread (200 wide blocks).
// All stored candidates have score > CONF_T.
// ---------------------------------------------------------------------------
__global__ __launch_bounds__(1024) void k_compact(const float* __restrict__ msc,
                                                  const int* __restrict__ Bv,
                                                  unsigned* __restrict__ cnt,
                                                  u64* __restrict__ cand) {
    int b = blockIdx.x / 25;
    int p = (blockIdx.x % 25) * 1024 + threadIdx.x;
    if (p >= NPRED) return;
    float s = msc[(size_t)b * NPRED + p];
    if (s > CONF_T) {
        unsigned bits = __float_as_uint(s);
        int bin = (int)(bits >> 14) - 0xFA00;
        bin = bin < 0 ? 0 : (bin > 1024 ? 1024 : bin);
        if (bin >= Bv[b]) {
            unsigned slot = atomicAdd(&cnt[b], 1u);
            if (slot < CAP)
                cand[(size_t)b * CAP + slot] = ((u64)(~bits) << 32) | (unsigned)p;
        }
    }
}

// ---------------------------------------------------------------------------
// K4: per-batch bitonic sort of <=2048 candidates (512 threads, 2 CE each)
// + gather top-1000. Key = (~score_bits << 32) | idx.
// Valid rows form a sorted prefix of length min(cnt, 1000) -> no valid array.
// ---------------------------------------------------------------------------
__global__ __launch_bounds__(512) void k_sort(const float* __restrict__ x,
                                              const int* __restrict__ cls,
                                              const unsigned* __restrict__ cnt,
                                              const u64* __restrict__ cand,
                                              float* __restrict__ det,
                                              float* __restrict__ offb) {
#pragma clang fp contract(off)
    __shared__ u64 keys[CAP];
    const int b = blockIdx.x, t = threadIdx.x;
    unsigned c = cnt[b]; if (c > CAP) c = CAP;
    for (int i = t; i < CAP; i += 512)
        keys[i] = (i < (int)c) ? cand[(size_t)b * CAP + i] : ~0ULL;
    __syncthreads();

    for (unsigned k = 2; k <= CAP; k <<= 1) {
        for (unsigned j = k >> 1; j > 0; j >>= 1) {
#pragma unroll
            for (int half = 0; half < 2; ++half) {
                unsigned tt = (unsigned)t + half * 512;
                unsigned i = ((tt & ~(j - 1)) << 1) | (tt & (j - 1));
                unsigned pi = i | j;
                bool up = ((i & k) == 0);
                u64 a = keys[i], d = keys[pi];
                bool sw = up ? (a > d) : (a < d);
                if (sw) { keys[i] = d; keys[pi] = a; }
            }
            __syncthreads();
        }
    }

    for (int r = t; r < NTOP; r += 512) {
        u64 key = keys[r];
        unsigned p = (unsigned)key;
        float score = __uint_as_float(~(unsigned)(key >> 32));
        bool v = score > CONF_T;
        float o0 = 0, o1 = 0, o2 = 0, o3 = 0, o4 = 0, o5 = 0;
        float f0 = 0, f1 = 0, f2 = 0, f3 = 0;
        if (v) {
            const float* xp = x + ((size_t)b * NPRED + p) * 85;
            float xc = xp[0], yc = xp[1], w = xp[2], h = xp[3];
            float hw = w * 0.5f, hh = h * 0.5f;
            o0 = xc - hw; o1 = yc - hh; o2 = xc + hw; o3 = yc + hh;
            o4 = score;
            float cf = (float)cls[(size_t)b * NPRED + p];
            o5 = cf;
            float co = cf * MAXWH;
            f0 = o0 + co; f1 = o1 + co; f2 = o2 + co; f3 = o3 + co;
        }
        size_t d6 = ((size_t)b * NTOP + r) * 6;
        det[d6 + 0] = o0; det[d6 + 1] = o1; det[d6 + 2] = o2;
        det[d6 + 3] = o3; det[d6 + 4] = o4; det[d6 + 5] = o5;
        size_t d4 = ((size_t)b * NTOP + r) * 4;
        offb[d4 + 0] = f0; offb[d4 + 1] = f1; offb[d4 + 2] = f2; offb[d4 + 3] = f3;
    }
}

// ---------------------------------------------------------------------------
// K5: 1000x1000 IoU bitmask, stored TRANSPOSED: maskT[b][w][i] = word w
// (columns 64w..64w+63) of row i. Coalesced writes here, coalesced row
// loads in k_scan. grid = 8 batches x 32 row-groups.
// ---------------------------------------------------------------------------
__global__ __launch_bounds__(256) void k_iou(const float* __restrict__ offb,
                                             u64* __restrict__ maskT) {
#pragma clang fp contract(off)
    __shared__ __align__(16) float4 bx4[NTOP];
    __shared__ float area[NTOP];
    const int b = blockIdx.x >> 5;
    const int rg = blockIdx.x & 31;
    const float4* ob = (const float4*)(offb + (size_t)b * NTOP * 4);
    for (int i = threadIdx.x; i < NTOP; i += 256) {
        float4 v = ob[i];
        bx4[i] = v;
        area[i] = (v.z - v.x) * (v.w - v.y);
    }
    __syncthreads();
    const int i = rg * 32 + (threadIdx.x & 31);
    const int q = threadIdx.x >> 5;            // 8 word-pairs
    if (i >= NTOP) return;
    float4 A = bx4[i];
    float areaA = area[i];
    u64* mt = maskT + (size_t)b * 16 * NTOP;
    for (int wi = 0; wi < 2; ++wi) {
        int w = q * 2 + wi;
        u64 bits = 0;
        int c0 = w * 64;
        for (int cc = 0; cc < 64; ++cc) {
            int col = c0 + cc;
            if (col >= NTOP) break;
            float4 Bb = bx4[col];              // broadcast read
            float ltx = fmaxf(A.x, Bb.x), lty = fmaxf(A.y, Bb.y);
            float rbx = fminf(A.z, Bb.z), rby = fminf(A.w, Bb.w);
            float ww = fmaxf(rbx - ltx, 0.0f), hh = fmaxf(rby - lty, 0.0f);
            float inter = ww * hh;
            float iou = inter / (((areaA + area[col]) - inter) + 1e-9f);
            if (iou > IOU_THR && col != i) bits |= (1ULL << cc);
        }
        mt[(size_t)w * NTOP + i] = bits;       // transposed, coalesced in i
    }
}

// ---------------------------------------------------------------------------
// K6: serial greedy scan, one wave per batch, symmetry trick (row & Kept).
// __launch_bounds__(64, 1): occupancy is irrelevant (8 blocks) — give the
// allocator the full VGPR file so the two 16-word row buffers stay register-
// resident. Round-5's 62 us was scratch round-trips (VGPR_Count=40 < the 64
// VGPRs the buffers need). Buffers ping-pong by unroll parity (no copies);
// valid bits come from cnt[b] (sorted prefix) — no valid array, no ballots.
// ---------------------------------------------------------------------------
__global__ __launch_bounds__(64, 1) void k_scan(const u64* __restrict__ maskT,
                                                const unsigned* __restrict__ cnt,
                                                const float* __restrict__ det,
                                                float* __restrict__ out) {
    const int b = blockIdx.x;
    const int lane = threadIdx.x;
    const u64* mt = maskT + (size_t)b * 16 * NTOP;
    __shared__ u64 kbs[16];
    int nv = (int)cnt[b]; if (nv > NTOP) nv = NTOP;  // valid = first nv rows

    u64 bufA[16], bufB[16];
#pragma unroll
    for (int w = 0; w < 16; ++w) bufA[w] = mt[(size_t)w * NTOP + lane];

    u64 Kp[16];
#pragma unroll
    for (int w = 0; w < 16; ++w) Kp[w] = 0;

#pragma unroll
    for (int g = 0; g < 16; ++g) {
        u64* cur = (g & 1) ? bufB : bufA;   // constant after unroll -> SROA-able
        u64* nxt = (g & 1) ? bufA : bufB;
        if (g + 1 < 16) {                   // prefetch next group (coalesced)
            int r = (g + 1) * 64 + lane;
            int rc = r < NTOP ? r : NTOP - 1;
#pragma unroll
            for (int w = 0; w < 16; ++w) nxt[w] = mt[(size_t)w * NTOP + rc];
        }
        // valid ballot from sorted-prefix property (pure SALU)
        int rem = nv - g * 64;
        u64 vb = rem >= 64 ? ~0ULL : (rem <= 0 ? 0ULL : ((1ULL << rem) - 1ULL));

        // pre-suppression from earlier groups via symmetry: my row & Kept
        u64 hitv = 0;
#pragma unroll
        for (int w = 0; w < 16; ++w) hitv |= cur[w] & Kp[w];
        u64 preS = __ballot(hitv != 0ULL);

        // intra-group serial chain on wave-uniform state (readlane-fed)
        u64 avail = vb & ~preS;
        const int mlo = (int)(unsigned)cur[g];
        const int mhi = (int)(unsigned)(cur[g] >> 32);
        u64 kb = 0;
#pragma unroll
        for (int tt = 0; tt < 64; ++tt) {
            unsigned lo2 = (unsigned)__builtin_amdgcn_readlane(mlo, tt);
            unsigned hi2 = (unsigned)__builtin_amdgcn_readlane(mhi, tt);
            u64 m = ((u64)hi2 << 32) | lo2;
            u64 bit = 1ULL << tt;
            kb |= avail & bit;
            avail &= ((avail & bit) != 0ULL) ? ~m : ~0ULL;
        }
        if (lane == 0) kbs[g] = kb;
        Kp[g] |= kb;                        // one uniform OR; no loads
    }
    __syncthreads();

    // masked output copy: rows are 3 x float2, float2 never straddles a row
    const float2* dp2 = (const float2*)(det + (size_t)b * NTOP * 6);
    float2* op2 = (float2*)(out + (size_t)b * NTOP * 6);
    for (int e = lane; e < NTOP * 3; e += 64) {
        int r = e / 3;
        u64 kb = kbs[r >> 6];
        bool keep = (kb >> (r & 63)) & 1ULL;
        float2 v = dp2[e];
        float2 z;
        z.x = keep ? v.x : 0.0f;
        z.y = keep ? v.y : 0.0f;
        op2[e] = z;
    }
}

// ---------------------------------------------------------------------------
extern "C" void kernel_launch(void* const* d_in, const int* in_sizes, int n_in,
                              void* d_out, int out_size, void* d_ws, size_t ws_size,
                              hipStream_t stream) {
    const float* x = (const float*)d_in[0];
    char* ws = (char*)d_ws;
    // layout (bytes):
    float* msc = (float*)(ws);                       //       0 .. 806400
    int* cls = (int*)(ws + 806400);                  //  806400 .. 1612800
    float* det = (float*)(ws + 1612800);             // 1612800 .. 1804800
    float* offb = (float*)(ws + 1804800);            // 1804800 .. 1932800
    unsigned* cnt = (unsigned*)(ws + 1932800);       // 1932800 .. 1932832 (32 B)
    u64* maskT = (u64*)(ws + 1964800);               // 1964800 .. 2988800
    // overlays in mask region (all consumed before k_iou writes maskT):
    unsigned* hist = (unsigned*)(ws + 1964800);      // 32800
    int* Bv = (int*)(ws + 1997600);                  // 32
    u64* cand = (u64*)(ws + 1997664);                // 131072

    hipMemsetAsync(hist, 0, 32864, stream);          // hist + Bv
    hipMemsetAsync(cnt, 0, 32, stream);              // cnt lives OUTSIDE maskT
    k_score<<<NB * SBPB, 128, 0, stream>>>(x, msc, cls, hist);
    k_boundary<<<1, 512, 0, stream>>>(hist, Bv);
    k_compact<<<NB * 25, 1024, 0, stream>>>(msc, Bv, cnt, cand);
    k_sort<<<NB, 512, 0, stream>>>(x, cls, cnt, cand, det, offb);
    k_iou<<<NB * 32, 256, 0, stream>>>(offb, maskT);
    k_scan<<<NB, 64, 0, stream>>>(maskT, cnt, det, (float*)d_out);
}

// Round 7
// 238.757 us; speedup vs baseline: 1.5018x; 1.5018x over previous
//
#include <hip/hip_runtime.h>
#include <stdint.h>

#define NB 8
#define NPRED 25200
#define NTOP 1000
#define NCLS 80
#define CONF_T 0.25f
#define IOU_THR 0.45f
#define MAXWH 4096.0f
#define CAP 2048
#define NBINS 1025
#define SBLK 128
#define SBPB 197   // ceil(25200/128): 197*128 = 25216

typedef unsigned long long u64;

// ---------------------------------------------------------------------------
// K1: score/class per pred + global histogram of score bits.
// Staging via global_load_lds width=16 (no VGPR round trip).
// ---------------------------------------------------------------------------
__global__ __launch_bounds__(128) void k_score(const float* __restrict__ x,
                                               float* __restrict__ msc,
                                               int* __restrict__ cls,
                                               unsigned* __restrict__ hist) {
#pragma clang fp contract(off)
    __shared__ __align__(16) float sm[SBLK * 85];
    const int b = blockIdx.x / SBPB;
    const int blk = blockIdx.x % SBPB;
    const int t = threadIdx.x;
    const int wave = t >> 6, lane = t & 63;
    const long long TOT4 = (long long)NB * NPRED * 85 / 4;  // 4,284,000
    const long long base4 = ((long long)b * NPRED + (long long)blk * SBLK) * 85 / 4;
    const float4* x4 = (const float4*)x;
    const int tile4 = SBLK * 85 / 4;  // 2720

    for (int k = 0; k < 22; ++k) {
        int ib = k * 128 + wave * 64;      // wave-uniform lds base (float4 units)
        int fi = ib + lane;
        if (fi < tile4) {
            long long gi = base4 + fi;
            if (gi >= TOT4) gi = TOT4 - 1;  // tail clamp (outputs guarded below)
            __builtin_amdgcn_global_load_lds(
                (const __attribute__((address_space(1))) void*)(x4 + gi),
                (__attribute__((address_space(3))) void*)(sm + (size_t)ib * 4),
                16, 0, 0);
        }
    }
    __syncthreads();

    int pred = blk * SBLK + t;
    if (pred < NPRED) {
        const float* p = &sm[t * 85];
        float obj = p[4];
        float best = p[5];
        int bid = 0;
        for (int c = 1; c < NCLS; ++c) {
            float v = p[5 + c];
            if (v > best) { best = v; bid = c; }  // strict >: first occurrence
        }
        float score = obj * best;
        int q = b * NPRED + pred;
        msc[q] = (score > CONF_T) ? score : -1.0f;
        cls[q] = bid;
        if (score > CONF_T) {
            int bin = (int)(__float_as_uint(score) >> 14) - 0xFA00;
            bin = bin < 0 ? 0 : (bin > 1024 ? 1024 : bin);
            atomicAdd(&hist[b * NBINS + bin], 1u);
        }
    }
}

// ---------------------------------------------------------------------------
// K2: compact candidates (bin >= B), one pred per thread (200 wide blocks).
// Boundary bin B recomputed by wave 0 of each block (folds the old
// k_boundary dispatch; ~2 us redundant work, saves a graph node).
// ---------------------------------------------------------------------------
__global__ __launch_bounds__(1024) void k_compact(const float* __restrict__ msc,
                                                  const unsigned* __restrict__ hist,
                                                  unsigned* __restrict__ cnt,
                                                  u64* __restrict__ cand) {
    __shared__ int sB;
    const int b = blockIdx.x / 25;
    if (threadIdx.x < 64) {   // wave 0: suffix-count boundary bin B
        const int lane = threadIdx.x;
        const unsigned* h = hist + b * NBINS;
        int hi = 1024 - 16 * lane;           // lane chunk: bins [hi-15, hi]
        unsigned sum = 0;
        for (int k = 0; k < 16; ++k) sum += h[hi - k];
        if (lane == 63) sum += h[0];
        unsigned v = sum;
        for (int d = 1; d < 64; d <<= 1) {
            unsigned o = __shfl_up(v, d);
            if (lane >= d) v += o;
        }
        unsigned excl = v - sum;             // count strictly above my chunk
        u64 ball = __ballot(v >= NTOP);
        int B = 0;
        if (ball != 0) {
            int sel = __builtin_ctzll(ball);
            if (lane == sel) {
                unsigned run = excl;
                for (int k = 0; k < 16; ++k) {
                    run += h[hi - k];
                    if (run >= NTOP) { B = hi - k; break; }
                }
            }
            B = __shfl(B, sel);
        }
        if (lane == 0) sB = B;
    }
    __syncthreads();
    const int B = sB;

    int p = (blockIdx.x % 25) * 1024 + threadIdx.x;
    if (p >= NPRED) return;
    float s = msc[(size_t)b * NPRED + p];
    if (s > CONF_T) {
        unsigned bits = __float_as_uint(s);
        int bin = (int)(bits >> 14) - 0xFA00;
        bin = bin < 0 ? 0 : (bin > 1024 ? 1024 : bin);
        if (bin >= B) {
            unsigned slot = atomicAdd(&cnt[b], 1u);
            if (slot < CAP)
                cand[(size_t)b * CAP + slot] = ((u64)(~bits) << 32) | (unsigned)p;
        }
    }
}

// ---------------------------------------------------------------------------
// K3: per-batch bitonic sort of <=2048 candidates (512 threads, 2 CE each)
// + gather top-1000. Key = (~score_bits << 32) | idx. Emits nv = number of
// valid rows (sorted prefix) for k_scan.
// ---------------------------------------------------------------------------
__global__ __launch_bounds__(512) void k_sort(const float* __restrict__ x,
                                              const int* __restrict__ cls,
                                              const unsigned* __restrict__ cnt,
                                              const u64* __restrict__ cand,
                                              float* __restrict__ det,
                                              float* __restrict__ offb,
                                              int* __restrict__ nvv) {
#pragma clang fp contract(off)
    __shared__ u64 keys[CAP];
    const int b = blockIdx.x, t = threadIdx.x;
    unsigned c = cnt[b]; if (c > CAP) c = CAP;
    if (t == 0) nvv[b] = (int)(c < NTOP ? c : NTOP);
    for (int i = t; i < CAP; i += 512)
        keys[i] = (i < (int)c) ? cand[(size_t)b * CAP + i] : ~0ULL;
    __syncthreads();

    for (unsigned k = 2; k <= CAP; k <<= 1) {
        for (unsigned j = k >> 1; j > 0; j >>= 1) {
#pragma unroll
            for (int half = 0; half < 2; ++half) {
                unsigned tt = (unsigned)t + half * 512;
                unsigned i = ((tt & ~(j - 1)) << 1) | (tt & (j - 1));
                unsigned pi = i | j;
                bool up = ((i & k) == 0);
                u64 a = keys[i], d = keys[pi];
                bool sw = up ? (a > d) : (a < d);
                if (sw) { keys[i] = d; keys[pi] = a; }
            }
            __syncthreads();
        }
    }

    for (int r = t; r < NTOP; r += 512) {
        u64 key = keys[r];
        unsigned p = (unsigned)key;
        float score = __uint_as_float(~(unsigned)(key >> 32));
        bool v = score > CONF_T;
        float o0 = 0, o1 = 0, o2 = 0, o3 = 0, o4 = 0, o5 = 0;
        float f0 = 0, f1 = 0, f2 = 0, f3 = 0;
        if (v) {
            const float* xp = x + ((size_t)b * NPRED + p) * 85;
            float xc = xp[0], yc = xp[1], w = xp[2], h = xp[3];
            float hw = w * 0.5f, hh = h * 0.5f;
            o0 = xc - hw; o1 = yc - hh; o2 = xc + hw; o3 = yc + hh;
            o4 = score;
            float cf = (float)cls[(size_t)b * NPRED + p];
            o5 = cf;
            float co = cf * MAXWH;
            f0 = o0 + co; f1 = o1 + co; f2 = o2 + co; f3 = o3 + co;
        }
        size_t d6 = ((size_t)b * NTOP + r) * 6;
        det[d6 + 0] = o0; det[d6 + 1] = o1; det[d6 + 2] = o2;
        det[d6 + 3] = o3; det[d6 + 4] = o4; det[d6 + 5] = o5;
        size_t d4 = ((size_t)b * NTOP + r) * 4;
        offb[d4 + 0] = f0; offb[d4 + 1] = f1; offb[d4 + 2] = f2; offb[d4 + 3] = f3;
    }
}

// ---------------------------------------------------------------------------
// K4: 1000x1000 IoU bitmask, stored TRANSPOSED: maskT[b][w][i] = word w
// (columns 64w..64w+63) of row i. Coalesced writes here, coalesced loads in
// k_scan. grid = 8 batches x 32 row-groups.
// ---------------------------------------------------------------------------
__global__ __launch_bounds__(256) void k_iou(const float* __restrict__ offb,
                                             u64* __restrict__ maskT) {
#pragma clang fp contract(off)
    __shared__ __align__(16) float4 bx4[NTOP];
    __shared__ float area[NTOP];
    const int b = blockIdx.x >> 5;
    const int rg = blockIdx.x & 31;
    const float4* ob = (const float4*)(offb + (size_t)b * NTOP * 4);
    for (int i = threadIdx.x; i < NTOP; i += 256) {
        float4 v = ob[i];
        bx4[i] = v;
        area[i] = (v.z - v.x) * (v.w - v.y);
    }
    __syncthreads();
    const int i = rg * 32 + (threadIdx.x & 31);
    const int q = threadIdx.x >> 5;            // 8 word-pairs
    if (i >= NTOP) return;
    float4 A = bx4[i];
    float areaA = area[i];
    u64* mt = maskT + (size_t)b * 16 * NTOP;
    for (int wi = 0; wi < 2; ++wi) {
        int w = q * 2 + wi;
        u64 bits = 0;
        int c0 = w * 64;
        for (int cc = 0; cc < 64; ++cc) {
            int col = c0 + cc;
            if (col >= NTOP) break;
            float4 Bb = bx4[col];              // broadcast read
            float ltx = fmaxf(A.x, Bb.x), lty = fmaxf(A.y, Bb.y);
            float rbx = fminf(A.z, Bb.z), rby = fminf(A.w, Bb.w);
            float ww = fmaxf(rbx - ltx, 0.0f), hh = fmaxf(rby - lty, 0.0f);
            float inter = ww * hh;
            float iou = inter / (((areaA + area[col]) - inter) + 1e-9f);
            if (iou > IOU_THR && col != i) bits |= (1ULL << cc);
        }
        mt[(size_t)w * NTOP + i] = bits;       // transposed, coalesced in i
    }
}

// ---------------------------------------------------------------------------
// K5: serial greedy scan, one wave per batch — ARRAY-FREE (rounds 3/5/6 all
// died on per-lane arrays demoted to scratch). Per-lane state: one u32
// `hitbits` (bit h = my row in group h is already suppressed) + one diag
// word. Per group: ballot(hitbits bit g) -> preS; 64-step readlane chain on
// the diag word; then FORWARD-propagate via symmetry: for each future group
// h, one coalesced load of word g of its rows, AND with uniform kb, set
// hitbits bit h. Fully unrolled -> all SSA scalars, nothing to spill.
// ---------------------------------------------------------------------------
__global__ __launch_bounds__(64, 1) void k_scan(const u64* __restrict__ maskT,
                                                const int* __restrict__ nvv,
                                                const float* __restrict__ det,
                                                float* __restrict__ out) {
    const int b = blockIdx.x;
    const int lane = threadIdx.x;
    const u64* mt = maskT + (size_t)b * 16 * NTOP;
    __shared__ u64 kbs[16];
    const int nv = nvv[b];

    unsigned hitbits = 0;
    u64 dcur = mt[lane];                    // group 0 diag word

#pragma unroll
    for (int g = 0; g < 16; ++g) {
        // prefetch next group's diag word (row clamped; garbage is vb-masked)
        u64 dnxt = 0;
        if (g + 1 < 16) {
            int rn = (g + 1) * 64 + lane;
            if (rn > NTOP - 1) rn = NTOP - 1;
            dnxt = mt[(size_t)(g + 1) * NTOP + rn];
        }

        // valid ballot from sorted-prefix property (pure SALU)
        int rem = nv - g * 64;
        u64 vb = rem >= 64 ? ~0ULL : (rem <= 0 ? 0ULL : ((1ULL << rem) - 1ULL));
        u64 preS = __ballot(((hitbits >> g) & 1u) != 0u);
        u64 avail = vb & ~preS;

        // intra-group serial chain on wave-uniform state (readlane-fed)
        const int mlo = (int)(unsigned)dcur;
        const int mhi = (int)(unsigned)(dcur >> 32);
        u64 kb = 0;
#pragma unroll
        for (int tt = 0; tt < 64; ++tt) {
            unsigned lo2 = (unsigned)__builtin_amdgcn_readlane(mlo, tt);
            unsigned hi2 = (unsigned)__builtin_amdgcn_readlane(mhi, tt);
            u64 m = ((u64)hi2 << 32) | lo2;
            u64 bit = 1ULL << tt;
            kb |= avail & bit;
            avail &= ((avail & bit) != 0ULL) ? ~m : ~0ULL;
        }
        if (lane == 0) kbs[g] = kb;

        // forward-propagate suppression to future groups (symmetry):
        // word g of row h*64+lane, ANDed with kept cols of group g
#pragma unroll
        for (int h = g + 1; h < 16; ++h) {
            int rh = h * 64 + lane;
            if (rh > NTOP - 1) rh = NTOP - 1;   // clamped rows are vb-masked
            u64 v = mt[(size_t)g * NTOP + rh];
            hitbits |= ((v & kb) != 0ULL) ? (1u << h) : 0u;
        }
        dcur = dnxt;
    }
    __syncthreads();

    // masked output copy: rows are 3 x float2, float2 never straddles a row
    const float2* dp2 = (const float2*)(det + (size_t)b * NTOP * 6);
    float2* op2 = (float2*)(out + (size_t)b * NTOP * 6);
    for (int e = lane; e < NTOP * 3; e += 64) {
        int r = e / 3;
        u64 kb = kbs[r >> 6];
        bool keep = (kb >> (r & 63)) & 1ULL;
        float2 v = dp2[e];
        float2 z;
        z.x = keep ? v.x : 0.0f;
        z.y = keep ? v.y : 0.0f;
        op2[e] = z;
    }
}

// ---------------------------------------------------------------------------
extern "C" void kernel_launch(void* const* d_in, const int* in_sizes, int n_in,
                              void* d_out, int out_size, void* d_ws, size_t ws_size,
                              hipStream_t stream) {
    const float* x = (const float*)d_in[0];
    char* ws = (char*)d_ws;
    // layout (bytes):
    float* msc = (float*)(ws);                       //       0 .. 806400
    int* cls = (int*)(ws + 806400);                  //  806400 .. 1612800
    float* det = (float*)(ws + 1612800);             // 1612800 .. 1804800
    float* offb = (float*)(ws + 1804800);            // 1804800 .. 1932800
    int* nvv = (int*)(ws + 1932800);                 // 1932800 .. 1932832 (32 B, outside overlay)
    u64* maskT = (u64*)(ws + 1964800);               // 1964800 .. 2988800
    // overlays in mask region (all consumed by k_sort before k_iou writes):
    unsigned* hist = (unsigned*)(ws + 1964800);      // 8*1025*4 = 32800
    unsigned* cnt = (unsigned*)(ws + 1997600);       // 32 (contiguous with hist)
    u64* cand = (u64*)(ws + 1997664);                // 8*2048*8 = 131072

    hipMemsetAsync(hist, 0, 32832, stream);          // hist + cnt, one node
    k_score<<<NB * SBPB, 128, 0, stream>>>(x, msc, cls, hist);
    k_compact<<<NB * 25, 1024, 0, stream>>>(msc, hist, cnt, cand);
    k_sort<<<NB, 512, 0, stream>>>(x, cls, cnt, cand, det, offb, nvv);
    k_iou<<<NB * 32, 256, 0, stream>>>(offb, maskT);
    k_scan<<<NB, 64, 0, stream>>>(maskT, nvv, det, (float*)d_out);
}